// Round 13
// baseline (303.241 us; speedup 1.0000x reference)
//
#include <hip/hip_runtime.h>

#define B_  8
#define C_  256
#define N_  16384
#define NM_ 128

typedef _Float16 f16x8 __attribute__((ext_vector_type(8)));
typedef float    f32x4 __attribute__((ext_vector_type(4)));

#define MFMA32(A, Bf, Cc) __builtin_amdgcn_mfma_f32_16x16x32_f16((A), (Bf), (Cc), 0, 0, 0)

// convert 8 fp32 (two float4) -> hi/lo f16x8, accumulate squared norm
#define CVT8(V0, V1, HI, LO, SQ)                                       \
    {                                                                  \
        float el_[8];                                                  \
        *(float4*)&el_[0] = (V0);                                      \
        *(float4*)&el_[4] = (V1);                                      \
        _Pragma("unroll")                                              \
        for (int e_ = 0; e_ < 8; ++e_) {                               \
            float v_ = el_[e_];                                        \
            _Float16 h_ = (_Float16)v_;                                \
            (HI)[e_] = h_;                                             \
            (LO)[e_] = (_Float16)(v_ - (float)h_);                     \
            (SQ) += v_ * v_;                                           \
        }                                                              \
    }

// ---------------- kernel 1: split-K fp16x2 MFMA GEMM ----------------
// BM=BN=256 (one block per (b,ks): X and Y each staged ONCE -> 268 MB total).
// 1024 threads = 16 waves (4x4), wave tile 64x64, 16x16x32 MFMA (full-rate K).
// BK=32; LDS [2][256][32] f16 x4 = 128 KB; [r][32] layout is conflict-free for
// both ds_write_b128 (stage) and ds_read_b128 (frags). Reg-stage + convert-once,
// double-buffered, one barrier per K-step. grid = KS*8 = 256 = 1 block/CU.
__global__ __launch_bounds__(1024)
void gemm_f16_kernel(const float* __restrict__ X,
                     const float* __restrict__ Y,
                     float* __restrict__ Gp,
                     float* __restrict__ x2p,
                     float* __restrict__ y2p,
                     int Kchunk) {
    __shared__ _Float16 aH[2][256][32];
    __shared__ _Float16 aL[2][256][32];
    __shared__ _Float16 bH[2][256][32];
    __shared__ _Float16 bL[2][256][32];

    // XCD-aware swizzle (grid = KS*8, multiple of 8)
    int cpx = gridDim.x >> 3;
    int lin = (blockIdx.x & 7) * cpx + (blockIdx.x >> 3);

    int b = lin & 7, ks = lin >> 3;
    int k0 = ks * Kchunk;
    int nsteps = Kchunk >> 5;   // BK=32

    int t = threadIdx.x;
    int lane = t & 63;
    int wid = t >> 6;                  // 0..15
    int wm = wid >> 2, wn = wid & 3;   // wave tile 64x64 at (wm*64, wn*64)
    int fr = lane & 15, ug = lane >> 4;

    // staging shares: row t>>2 (0..255), k-slice (t&3)*8 -- for both A and B
    int sr = t >> 2, sk = (t & 3) * 8;
    const float* ax = X + (size_t)(b * C_ + sr) * N_ + k0 + sk;
    const float* by = Y + (size_t)(b * C_ + sr) * N_ + k0 + sk;

    f32x4 acc[4][4] = {};
    float sx = 0.f, sy = 0.f;
    float4 vA0, vA1, vB0, vB1;

    auto loads = [&](int i) {
        vA0 = *(const float4*)(ax + i * 32);
        vA1 = *(const float4*)(ax + i * 32 + 4);
        vB0 = *(const float4*)(by + i * 32);
        vB1 = *(const float4*)(by + i * 32 + 4);
    };
    auto convert_store = [&](int sl) {
        f16x8 h, l;
        CVT8(vA0, vA1, h, l, sx);
        *(f16x8*)&aH[sl][sr][sk] = h;
        *(f16x8*)&aL[sl][sr][sk] = l;
        CVT8(vB0, vB1, h, l, sy);
        *(f16x8*)&bH[sl][sr][sk] = h;
        *(f16x8*)&bL[sl][sr][sk] = l;
    };

    // prologue
    loads(0);
    convert_store(0);
    __syncthreads();

    for (int i = 0; i < nsteps; ++i) {
        int sl = i & 1;
        if (i + 1 < nsteps) loads(i + 1);      // issue early, land during MFMA phase
        __builtin_amdgcn_sched_barrier(0);

        // two mf-halves to cap live A-fragment registers at 16
#pragma unroll
        for (int h2 = 0; h2 < 2; ++h2) {
            f16x8 aHi[2], aLo[2];
#pragma unroll
            for (int q = 0; q < 2; ++q) {
                int mr = wm * 64 + (h2 * 2 + q) * 16 + fr;
                aHi[q] = *(const f16x8*)&aH[sl][mr][ug * 8];
                aLo[q] = *(const f16x8*)&aL[sl][mr][ug * 8];
            }
            __builtin_amdgcn_s_setprio(1);
#pragma unroll
            for (int nf = 0; nf < 4; ++nf) {
                int nr = wn * 64 + nf * 16 + fr;
                f16x8 bHi = *(const f16x8*)&bH[sl][nr][ug * 8];
                f16x8 bLo = *(const f16x8*)&bL[sl][nr][ug * 8];
#pragma unroll
                for (int q = 0; q < 2; ++q) {
                    int mf = h2 * 2 + q;
                    acc[mf][nf] = MFMA32(aHi[q], bHi, acc[mf][nf]);
                    acc[mf][nf] = MFMA32(aHi[q], bLo, acc[mf][nf]);
                    acc[mf][nf] = MFMA32(aLo[q], bHi, acc[mf][nf]);
                }
            }
            __builtin_amdgcn_s_setprio(0);
        }

        if (i + 1 < nsteps) convert_store(sl ^ 1);
        __syncthreads();
    }

    // norm partials: each row's 32-k slice staged by 4 threads (t&3)
    sx += __shfl_xor(sx, 1);
    sx += __shfl_xor(sx, 2);
    sy += __shfl_xor(sy, 1);
    sy += __shfl_xor(sy, 2);
    if ((t & 3) == 0) {
        x2p[(ks * B_ + b) * C_ + sr] = sx;
        y2p[(ks * B_ + b) * C_ + sr] = sy;
    }

    // write G partial; C-layout: col = lane&15, row = (lane>>4)*4 + r
    size_t gbase = (size_t)(ks * B_ + b) * C_ * C_;
#pragma unroll
    for (int mf = 0; mf < 4; ++mf)
#pragma unroll
        for (int nf = 0; nf < 4; ++nf) {
            int rr = wm * 64 + mf * 16 + (lane >> 4) * 4;
            int cc = wn * 64 + nf * 16 + (lane & 15);
#pragma unroll
            for (int r = 0; r < 4; ++r)
                Gp[gbase + (size_t)(rr + r) * C_ + cc] = acc[mf][nf][r];
        }
}

// ---------------- kernel 2: reduce split-K, d2 = x2+y2-2G, argmin over j (tie -> smaller j) ----------------
__global__ __launch_bounds__(256) void argmin_kernel(const float* __restrict__ Gp,
                                                     const float* __restrict__ x2p,
                                                     const float* __restrict__ y2p,
                                                     float* __restrict__ minval,
                                                     int* __restrict__ minidx,
                                                     int KS) {
    int bi = blockIdx.x;           // b*C + i
    int b = bi >> 8;
    int i = bi & 255;
    int j = threadIdx.x;           // 0..255 == C

    float g = 0.f, sx = 0.f, sy = 0.f;
    for (int ks = 0; ks < KS; ++ks) {
        g  += Gp[((size_t)(ks * B_ + b) * C_ + i) * C_ + j];
        sx += x2p[(ks * B_ + b) * C_ + i];
        sy += y2p[(ks * B_ + b) * C_ + j];
    }

    float v = sx + sy - 2.f * g;
    int idx = j;
#pragma unroll
    for (int off = 32; off > 0; off >>= 1) {
        float v2 = __shfl_down(v, off);
        int i2 = __shfl_down(idx, off);
        if (v2 < v || (v2 == v && i2 < idx)) { v = v2; idx = i2; }
    }
    __shared__ float wv[4];
    __shared__ int wi[4];
    int lane = threadIdx.x & 63, wid = threadIdx.x >> 6;
    if (lane == 0) { wv[wid] = v; wi[wid] = idx; }
    __syncthreads();
    if (threadIdx.x == 0) {
        for (int w = 1; w < 4; ++w)
            if (wv[w] < v || (wv[w] == v && wi[w] < idx)) { v = wv[w]; idx = wi[w]; }
        minval[bi] = v;
        minidx[bi] = idx;
    }
}

// ---------------- kernel 3: per-batch stable top-128 selection + compaction ----------------
__global__ __launch_bounds__(256) void select_kernel(const float* __restrict__ minval,
                                                     const int* __restrict__ minidx,
                                                     int* __restrict__ nn) {
    int b = blockIdx.x;
    int i = threadIdx.x;           // channel
    __shared__ float vals[C_];
    __shared__ int wcnt[4];

    float v = minval[b * C_ + i];
    vals[i] = v;
    __syncthreads();

    int rank = 0;
    for (int tt = 0; tt < C_; ++tt) {
        float u = vals[tt];
        rank += (u < v) || (u == v && tt < i);
    }
    bool flag = rank < NM_;

    unsigned long long m = __ballot(flag);
    int lane = i & 63, wid = i >> 6;
    if (lane == 0) wcnt[wid] = (int)__popcll(m);
    __syncthreads();
    int off = 0;
    for (int w = 0; w < wid; ++w) off += wcnt[w];
    int pos = off + (int)__popcll(m & ((1ULL << lane) - 1ULL));
    if (flag) nn[b * NM_ + pos] = minidx[b * C_ + i];
}

// ---------------- kernel 4: gather selected Ym rows ----------------
__global__ __launch_bounds__(256) void gather_kernel(const float* __restrict__ Y,
                                                     const int* __restrict__ nn,
                                                     float* __restrict__ out) {
    int blk = blockIdx.x;
    int b = blk >> 7;
    int m = blk & 127;
    int src = nn[b * NM_ + m];
    const float4* s = (const float4*)(Y + ((size_t)b * C_ + src) * N_);
    float4* d = (float4*)(out + ((size_t)b * NM_ + m) * N_);
    for (int tt = threadIdx.x; tt < N_ / 4; tt += 256) d[tt] = s[tt];
}

extern "C" void kernel_launch(void* const* d_in, const int* in_sizes, int n_in,
                              void* d_out, int out_size, void* d_ws, size_t ws_size,
                              hipStream_t stream) {
    const float* X = (const float*)d_in[0];
    const float* Y = (const float*)d_in[1];
    float* out = (float*)d_out;

    // choose split-K factor by available workspace (target 32 -> grid 256 = 1 block/CU)
    size_t favail = ws_size / 4;
    int KS = 1;
    while (KS < 32) {
        int KS2 = KS * 2;
        size_t need = (size_t)KS2 * B_ * C_ * C_          // Gp
                    + (size_t)KS2 * 2 * B_ * C_           // x2p, y2p
                    + 2 * B_ * C_ + B_ * NM_;             // minval/minidx/nn
        if (need > favail) break;
        KS = KS2;
    }
    int Kchunk = N_ / KS;

    float* minval = (float*)d_ws;
    int* minidx = (int*)(minval + B_ * C_);
    int* nn = minidx + B_ * C_;
    float* x2p = (float*)(nn + B_ * NM_);
    float* y2p = x2p + (size_t)KS * B_ * C_;
    float* Gp = y2p + (size_t)KS * B_ * C_;

    hipLaunchKernelGGL(gemm_f16_kernel, dim3(KS * 8), dim3(1024), 0, stream, X, Y, Gp, x2p, y2p, Kchunk);
    hipLaunchKernelGGL(argmin_kernel, dim3(B_ * C_), dim3(256), 0, stream, Gp, x2p, y2p, minval, minidx, KS);
    hipLaunchKernelGGL(select_kernel, dim3(B_), dim3(256), 0, stream, minval, minidx, nn);
    hipLaunchKernelGGL(gather_kernel, dim3(B_ * NM_), dim3(256), 0, stream, Y, nn, out);
}